// Round 30
// baseline (291.176 us; speedup 1.0000x reference)
//
#include <hip/hip_runtime.h>
#include <stdint.h>

#define B_ 8
#define S_ 4096
#define D_ 192
#define M_ (B_*S_)
#define VTILE 13824  // V fp8 tile image: 192 rows x (64 s + 8 pad) bytes
#define KTILE 12800  // K fp8 tile image: 64 rows x (192 + 8 pad) bytes
#define NT_ 64       // KV tiles per sequence (S/64)

typedef short v8s __attribute__((ext_vector_type(8)));
typedef float v4f __attribute__((ext_vector_type(4)));
typedef unsigned long long ull;

static __device__ __forceinline__ unsigned short f2bf(float f){
  union{float f; unsigned u;} v; v.f=f;
  unsigned u = v.u;
  unsigned r = (u + 0x7fffu + ((u>>16)&1u))>>16;
  return (unsigned short)r;
}
static __device__ __forceinline__ float fexp2(float x){
  return __builtin_amdgcn_exp2f(x);
}

// ---- fp8 e4m3fn pack ----
static __device__ __forceinline__ unsigned sw_fp8(float x){
  union{float f; unsigned u;} v; v.f = x;
  unsigned s = (v.u >> 24) & 0x80u;
  float a = fabsf(x);
  if (a < 0.001953125f) return s;
  if (a >= 240.f) return s | 0x7Eu;
  if (a < 0.015625f) {
    int m = (int)(a*512.f + 0.5f); if(m>7) m=7;
    return s | (unsigned)m;
  }
  int e = (int)((v.u >> 23) & 0xff) - 127;
  unsigned mant = (v.u >> 20) & 0x7u;
  unsigned rest = v.u & 0xFFFFFu;
  if (rest > 0x80000u || (rest == 0x80000u && (mant&1u))) mant++;
  unsigned ee = (unsigned)(e + 7);
  if (mant == 8u){ mant = 0u; ee++; }
  return s | (ee<<3) | mant;
}
template<bool HI>
static __device__ __forceinline__ unsigned pk8(float a, float b, unsigned old){
#if __has_builtin(__builtin_amdgcn_cvt_pk_fp8_f32)
  return __builtin_amdgcn_cvt_pk_fp8_f32(a, b, old, HI);
#else
  unsigned p = sw_fp8(a) | (sw_fp8(b)<<8);
  return HI ? ((old & 0x0000FFFFu) | (p<<16)) : ((old & 0xFFFF0000u) | p);
#endif
}

typedef const __attribute__((address_space(1))) unsigned int gu32;
typedef __attribute__((address_space(3))) unsigned int lu32;
#define GLL16(gp, lp) __builtin_amdgcn_global_load_lds((gu32*)(gp), (lu32*)(lp), 16, 0, 0)

// ---------------- weight conversion fp32 -> bf16 ----------------
__global__ void cvt_w_kernel(const float* w0,const float* w1,const float* w2,const float* w3,
                             const float* w4,const float* w5,const float* w6,const float* w7,
                             unsigned short* dst){
  int w = blockIdx.y;
  const float* src;
  switch(w){
    case 0: src=w0; break; case 1: src=w1; break; case 2: src=w2; break; case 3: src=w3; break;
    case 4: src=w4; break; case 5: src=w5; break; case 6: src=w6; break; default: src=w7; break;
  }
  int i = blockIdx.x*256 + threadIdx.x;
  float v = src[i];
  if(w==0 || w==4 || w==1 || w==5) v *= 0.32267249f;   // sqrt(log2(e)/sqrt(192))
  dst[(size_t)w*36864 + i] = f2bf(v);
}

// ---------------- fused QKV projection, split by path ----------------
// Q8 fp8 [row][192]; K fp8 tile images [path][b][64][64][200B];
// V fp8 tile images [path][b][64][192][72B]. Block covers exactly one tile.
__global__ __launch_bounds__(256) void proj_kernel(
    const float* __restrict__ x, const unsigned short* __restrict__ Wb,
    unsigned char* __restrict__ Q8g, unsigned char* __restrict__ K8t,
    unsigned char* __restrict__ V8)
{
  __shared__ __align__(16) unsigned char Vstage8[VTILE];   // 13.8 KB
  const size_t MDB = (size_t)M_*D_;
  int path = blockIdx.y;
  int tid = threadIdx.x;
  int wid = tid>>6, lane = tid&63;
  int lr = lane&15, lg = lane>>4, kb = lg*8;
  int m0 = blockIdx.x*64 + wid*16;
  int row = m0 + lr;

  v8s a[6];
  #pragma unroll
  for(int c=0;c<6;c++){
    const float* xp = &x[(size_t)row*D_ + c*32 + kb];
    float4 f0 = *(const float4*)xp;
    float4 f1 = *(const float4*)(xp+4);
    v8s t;
    t[0]=(short)f2bf(f0.x); t[1]=(short)f2bf(f0.y); t[2]=(short)f2bf(f0.z); t[3]=(short)f2bf(f0.w);
    t[4]=(short)f2bf(f1.x); t[5]=(short)f2bf(f1.y); t[6]=(short)f2bf(f1.z); t[7]=(short)f2bf(f1.w);
    a[c]=t;
  }
  int bidx = m0 / S_;
  int sb   = (blockIdx.x*64) % S_;       // block s-base = one 64-row tile
  int tile = sb >> 6;
  int sloc = wid*16 + lg*4;              // local s (0..63)

  // ---- Q: fp8 linear [row][192] ----
  {
    const unsigned short* W = Wb + (size_t)(path*4 + 0)*36864;
    unsigned char* dst = Q8g + (size_t)path*MDB;
    #pragma unroll
    for(int nt=0; nt<12; nt++){
      v4f acc = {0.f,0.f,0.f,0.f};
      int n = nt*16 + lr;
      #pragma unroll
      for(int c=0;c<6;c++){
        v8s bfr = *(const v8s*)&W[(size_t)n*D_ + c*32 + kb];
        acc = __builtin_amdgcn_mfma_f32_16x16x32_bf16(a[c], bfr, acc, 0,0,0);
      }
      int col = nt*16 + lr;
      int r0 = m0 + lg*4;
      #pragma unroll
      for(int r=0;r<4;r++){
        unsigned p = pk8<false>(acc[r], 0.f, 0u);
        dst[(size_t)(r0+r)*D_ + col] = (unsigned char)(p & 0xFF);
      }
    }
  }
  // ---- K: fp8 tile image [64][200B] ----
  {
    const unsigned short* W = Wb + (size_t)(path*4 + 1)*36864;
    unsigned char* dstK = K8t + (((size_t)path*B_ + bidx)*NT_ + tile)*KTILE;
    #pragma unroll
    for(int nt=0; nt<12; nt++){
      v4f acc = {0.f,0.f,0.f,0.f};
      int n = nt*16 + lr;
      #pragma unroll
      for(int c=0;c<6;c++){
        v8s bfr = *(const v8s*)&W[(size_t)n*D_ + c*32 + kb];
        acc = __builtin_amdgcn_mfma_f32_16x16x32_bf16(a[c], bfr, acc, 0,0,0);
      }
      int col = nt*16 + lr;
      #pragma unroll
      for(int r=0;r<4;r++){
        unsigned p = pk8<false>(acc[r], 0.f, 0u);
        dstK[(size_t)(sloc+r)*200 + col] = (unsigned char)(p & 0xFF);
      }
    }
  }
  // ---- V: fp8 tile image [192][72B] via LDS stage ----
  {
    const unsigned short* W = Wb + (size_t)(path*4 + 2)*36864;
    #pragma unroll
    for(int nt=0; nt<12; nt++){
      v4f acc = {0.f,0.f,0.f,0.f};
      int n = nt*16 + lr;
      #pragma unroll
      for(int c=0;c<6;c++){
        v8s bfr = *(const v8s*)&W[(size_t)n*D_ + c*32 + kb];
        acc = __builtin_amdgcn_mfma_f32_16x16x32_bf16(a[c], bfr, acc, 0,0,0);
      }
      int col = nt*16 + lr;
      unsigned pk4 = pk8<false>(acc[0], acc[1], 0u);
      pk4 = pk8<true>(acc[2], acc[3], pk4);
      *(unsigned*)&Vstage8[col*72 + sloc] = pk4;
    }
    __syncthreads();
    unsigned char* dstV = V8 + (((size_t)path*B_ + bidx)*NT_ + tile)*VTILE;
    #pragma unroll
    for(int j=0;j<4;j++){
      int i = tid + j*256;                 // 864 chunks of 16B
      if(i<864) *(v8s*)&dstV[i*16] = *(const v8s*)&Vstage8[i*16];
    }
  }
}

// ---------------- flash attention: fp8, tile 64, counted-vmcnt pipeline -----
// grid (32,8,2) XCD-remapped, 512 thr (8w x 16q). 64 iterations, triple-
// buffered K and V, 2-tile prefetch depth. End-of-iter wait is a COUNTED
// vmcnt (per-wave issue count) so next-next tile's DMAs stay in flight
// across the barrier (T4); only the last two iters drain fully.
__global__ __launch_bounds__(512,4) void attn_kernel(
    const unsigned char* __restrict__ Q8g,
    const unsigned char* __restrict__ K8t,
    const unsigned char* __restrict__ V8,
    unsigned short* __restrict__ Ob)
{
  __shared__ __align__(16) unsigned char KL[3][KTILE];      // 38.4 KB
  __shared__ __align__(16) unsigned char VL8[3][VTILE];     // 41.5 KB (78 KB)

  int flat = blockIdx.x + 32*blockIdx.y + 256*blockIdx.z;
  int w = (flat&7)*64 + (flat>>3);   // bijective on [0,512)
  int qi = w & 31;
  int b  = (w>>5) & 7;
  int z  = w>>8;

  const size_t MDB = (size_t)M_*D_;
  const unsigned char* Q8 = Q8g + (size_t)z*MDB;
  const unsigned char* Kp = K8t + ((size_t)z*B_ + b)*NT_*KTILE;
  const unsigned char* Vp = V8 + ((size_t)z*B_ + b)*NT_*VTILE;
  unsigned short* O = Ob + (size_t)z*MDB;

  int q0 = qi*128;
  int tid = threadIdx.x, wid=tid>>6, lane=tid&63;
  int lr = lane&15, lg = lane>>4;
  size_t bK = (size_t)b*S_*D_;
  int qrow0 = q0 + wid*16;

  long qf8[6];
  {
    const unsigned char* qp = Q8 + bK + (size_t)(qrow0 + lr)*D_;
    #pragma unroll
    for(int c=0;c<6;c++) qf8[c] = *(const long*)(qp + c*32 + lg*8);
  }
  float lsum = 0.f;
  v4f oacc[12];
  #pragma unroll
  for(int e=0;e<12;e++) oacc[e] = (v4f){0.f,0.f,0.f,0.f};

  bool k2 = tid < 288;    // 800 K chunks = 512 + 288 (wave 4 partial)
  bool v2 = tid < 352;    // 864 V chunks = 512 + 352 (wave 5 partial)

  // per-wave DMA issue counts (vmcnt retires in order -> counted wait
  // drains exactly the previous tile's loads): w0-3:4, w4:4, w5:3, w6-7:2
  auto wait_counted = [&](){
    if(wid < 5)       asm volatile("s_waitcnt vmcnt(4)" ::: "memory");
    else if(wid == 5) asm volatile("s_waitcnt vmcnt(3)" ::: "memory");
    else              asm volatile("s_waitcnt vmcnt(2)" ::: "memory");
  };

  auto stage = [&](int t, int buf){
    const unsigned char* kg = Kp + (size_t)t*KTILE;
    const unsigned char* vg = Vp + (size_t)t*VTILE;
    GLL16(kg + tid*16, &KL[buf][tid*16]);
    if(k2) GLL16(kg + (512+tid)*16, &KL[buf][(512+tid)*16]);
    GLL16(vg + tid*16, &VL8[buf][tid*16]);
    if(v2) GLL16(vg + (512+tid)*16, &VL8[buf][(512+tid)*16]);
  };
  auto do_qk = [&](int kcur, v4f sacc[4]){
    __builtin_amdgcn_s_setprio(1);
    #pragma unroll
    for(int ct=0; ct<4; ct++){
      v4f s = {0.f,0.f,0.f,0.f};
      const unsigned char* rb = &KL[kcur][(ct*16+lr)*200];
      #pragma unroll
      for(int c=0;c<6;c++){
        long kf8 = *(const long*)(rb + c*32 + lg*8);
        s = __builtin_amdgcn_mfma_f32_16x16x32_fp8_fp8(kf8, qf8[c], s, 0,0,0);
      }
      sacc[ct]=s;
    }
    __builtin_amdgcn_s_setprio(0);
  };
  auto do_softmax = [&](v4f sacc[4], long pa8[2]){
    #pragma unroll
    for(int h=0; h<2; h++){
      v4f s0 = sacc[2*h], s1 = sacc[2*h+1];
      float p00=fexp2(s0[0]), p01=fexp2(s0[1]), p02=fexp2(s0[2]), p03=fexp2(s0[3]);
      float p10=fexp2(s1[0]), p11=fexp2(s1[1]), p12=fexp2(s1[2]), p13=fexp2(s1[3]);
      lsum += ((p00+p01)+(p02+p03)) + ((p10+p11)+(p12+p13));
      unsigned A = pk8<false>(p00,p01,0u); A = pk8<true>(p02,p03,A);
      unsigned Bx= pk8<false>(p10,p11,0u); Bx= pk8<true>(p12,p13,Bx);
      asm("v_permlane32_swap_b32 %0, %1" : "+v"(Bx), "+v"(A));
      asm("v_permlane16_swap_b32 %0, %1" : "+v"(Bx), "+v"(A));
      pa8[h] = (long)(((ull)Bx<<32) | (ull)A);
    }
  };
  auto do_pv = [&](int vcur, long pa8[2]){
    __builtin_amdgcn_s_setprio(1);
    #pragma unroll
    for(int e=0;e<12;e++){
      const unsigned char* vr = &VL8[vcur][(e*16+lr)*72 + lg*8];
      long vb0 = *(const long*)(vr);
      long vb1 = *(const long*)(vr + 32);
      oacc[e] = __builtin_amdgcn_mfma_f32_16x16x32_fp8_fp8(pa8[0], vb0, oacc[e], 0,0,0);
      oacc[e] = __builtin_amdgcn_mfma_f32_16x16x32_fp8_fp8(pa8[1], vb1, oacc[e], 0,0,0);
    }
    __builtin_amdgcn_s_setprio(0);
  };

  // prologue: tile 0 resident; tile 1 in flight
  stage(0, 0);
  asm volatile("s_waitcnt vmcnt(0)" ::: "memory");
  __syncthreads();
  stage(1, 1);

  for(int t=0; t<NT_; t++){
    int cur = t % 3;
    v4f sacc[4];
    do_qk(cur, sacc);
    if(t < NT_-2) stage(t+2, (t+2)%3);
    __builtin_amdgcn_sched_barrier(0);
    long pa8[2];
    do_softmax(sacc, pa8);
    do_pv(cur, pa8);
    // drain tile t+1's DMAs (issued last iter); keep t+2's in flight
    if(t < NT_-2) wait_counted();
    else          asm volatile("s_waitcnt vmcnt(0)" ::: "memory");
    __syncthreads();
  }

  // epilogue: per-lane sums (q-row = lr) -> row inverses -> O write (bf16)
  float ps = lsum;
  ps += __shfl_xor(ps, 16);
  ps += __shfl_xor(ps, 32);
  float iv = 1.0f/ps;
  float invr[4];
  #pragma unroll
  for(int r=0;r<4;r++) invr[r] = __shfl(iv, lg*4+r, 16);
  size_t orow0 = ((size_t)b*S_ + qrow0 + lg*4)*D_;
  #pragma unroll
  for(int e=0;e<12;e++){
    #pragma unroll
    for(int r=0;r<4;r++){
      O[orow0 + (size_t)r*D_ + e*16 + lr] = f2bf(oacc[e][r]*invr[r]);
    }
  }
}

// ---------------- final: column-half GEMM split ----------------
__global__ __launch_bounds__(256) void final_kernel(
  const float* __restrict__ x,
  const unsigned short* __restrict__ Or,
  const unsigned short* __restrict__ Ow,
  const unsigned short* __restrict__ WoR,
  const unsigned short* __restrict__ WoW,
  float* __restrict__ out)
{
  int halfn = blockIdx.y;
  int tid=threadIdx.x, wid=tid>>6, lane=tid&63;
  int lr=lane&15, lg=lane>>4, kb=lg*8;
  int m0 = blockIdx.x*64 + wid*16;
  int arow = m0 + lr;
  v8s ar[6], aw[6];
  #pragma unroll
  for(int c=0;c<6;c++){
    ar[c] = *(const v8s*)&Or[(size_t)arow*D_ + c*32 + kb];
    aw[c] = *(const v8s*)&Ow[(size_t)arow*D_ + c*32 + kb];
  }
  int bidx = m0 / S_;
  float rf = x[(size_t)bidx*S_*D_ + 156];
  float wf = x[(size_t)bidx*S_*D_ + 157];
  #pragma unroll
  for(int ntl=0; ntl<6; ntl++){
    int nt = halfn*6 + ntl;
    v4f accR={0.f,0.f,0.f,0.f}, accW={0.f,0.f,0.f,0.f};
    int n = nt*16 + lr;
    #pragma unroll
    for(int c=0;c<6;c++){
      v8s br = *(const v8s*)&WoR[(size_t)n*D_ + c*32 + kb];
      accR = __builtin_amdgcn_mfma_f32_16x16x32_bf16(ar[c], br, accR,0,0,0);
      v8s bw = *(const v8s*)&WoW[(size_t)n*D_ + c*32 + kb];
      accW = __builtin_amdgcn_mfma_f32_16x16x32_bf16(aw[c], bw, accW,0,0,0);
    }
    #pragma unroll
    for(int r=0;r<4;r++){
      int row = m0 + lg*4 + r;
      int col = nt*16 + lr;
      float xv = x[(size_t)row*D_ + col];
      float val = xv + rf*(accR[r]-xv) + wf*(accW[r]-xv);
      if(col==156||col==157) val = 0.f;
      else if(col==158) val = rf+wf;
      out[(size_t)row*D_ + col] = val;
    }
  }
}

extern "C" void kernel_launch(void* const* d_in, const int* in_sizes, int n_in,
                              void* d_out, int out_size, void* d_ws, size_t ws_size,
                              hipStream_t stream) {
  const float* x = (const float*)d_in[0];
  char* wsb = (char*)d_ws;
  const size_t WSZ = 36864;
  const size_t MDB = (size_t)M_*D_;
  const size_t K8SZ = (size_t)2*B_*NT_*KTILE;                  // 13.1 MB
  const size_t V8SZ = (size_t)2*B_*NT_*VTILE;                  // 14.2 MB
  unsigned short* Wb  = (unsigned short*)wsb;                  // 0.59 MB
  unsigned char*  Q8  = (unsigned char*)(wsb + 8*WSZ*2);       // 12.6 MB
  unsigned char*  K8t = Q8 + 2*MDB;                            // 13.1 MB
  unsigned char*  V8  = K8t + K8SZ;                            // 14.2 MB
  unsigned short* Ob  = (unsigned short*)(V8 + V8SZ);          // 25.2 MB

  cvt_w_kernel<<<dim3(144,8),256,0,stream>>>(
      (const float*)d_in[1],(const float*)d_in[2],(const float*)d_in[3],(const float*)d_in[4],
      (const float*)d_in[5],(const float*)d_in[6],(const float*)d_in[7],(const float*)d_in[8], Wb);

  proj_kernel<<<dim3(512,2),256,0,stream>>>(x, Wb, Q8, K8t, V8);
  attn_kernel<<<dim3(32,8,2),512,0,stream>>>(Q8, K8t, V8, Ob);
  final_kernel<<<dim3(512,2),256,0,stream>>>(x, Ob, Ob + MDB,
                                             Wb+3*WSZ, Wb+7*WSZ, (float*)d_out);
}

// Round 31
// 290.996 us; speedup vs baseline: 1.0006x; 1.0006x over previous
//
#include <hip/hip_runtime.h>
#include <stdint.h>

#define B_ 8
#define S_ 4096
#define D_ 192
#define M_ (B_*S_)
#define VTILE 13824  // V fp8 tile image: 192 rows x (64 s + 8 pad) bytes
#define KTILE 12800  // K fp8 tile image: 64 rows x (192 + 8 pad) bytes
#define NT_ 64       // KV tiles per sequence (S/64)

typedef short v8s __attribute__((ext_vector_type(8)));
typedef float v4f __attribute__((ext_vector_type(4)));
typedef unsigned long long ull;

static __device__ __forceinline__ unsigned short f2bf(float f){
  union{float f; unsigned u;} v; v.f=f;
  unsigned u = v.u;
  unsigned r = (u + 0x7fffu + ((u>>16)&1u))>>16;
  return (unsigned short)r;
}
static __device__ __forceinline__ float fexp2(float x){
  return __builtin_amdgcn_exp2f(x);
}

// ---- fp8 e4m3fn pack ----
static __device__ __forceinline__ unsigned sw_fp8(float x){
  union{float f; unsigned u;} v; v.f = x;
  unsigned s = (v.u >> 24) & 0x80u;
  float a = fabsf(x);
  if (a < 0.001953125f) return s;
  if (a >= 240.f) return s | 0x7Eu;
  if (a < 0.015625f) {
    int m = (int)(a*512.f + 0.5f); if(m>7) m=7;
    return s | (unsigned)m;
  }
  int e = (int)((v.u >> 23) & 0xff) - 127;
  unsigned mant = (v.u >> 20) & 0x7u;
  unsigned rest = v.u & 0xFFFFFu;
  if (rest > 0x80000u || (rest == 0x80000u && (mant&1u))) mant++;
  unsigned ee = (unsigned)(e + 7);
  if (mant == 8u){ mant = 0u; ee++; }
  return s | (ee<<3) | mant;
}
template<bool HI>
static __device__ __forceinline__ unsigned pk8(float a, float b, unsigned old){
#if __has_builtin(__builtin_amdgcn_cvt_pk_fp8_f32)
  return __builtin_amdgcn_cvt_pk_fp8_f32(a, b, old, HI);
#else
  unsigned p = sw_fp8(a) | (sw_fp8(b)<<8);
  return HI ? ((old & 0x0000FFFFu) | (p<<16)) : ((old & 0xFFFF0000u) | p);
#endif
}

typedef const __attribute__((address_space(1))) unsigned int gu32;
typedef __attribute__((address_space(3))) unsigned int lu32;
#define GLL16(gp, lp) __builtin_amdgcn_global_load_lds((gu32*)(gp), (lu32*)(lp), 16, 0, 0)

// ---------------- weight conversion fp32 -> bf16 ----------------
__global__ void cvt_w_kernel(const float* w0,const float* w1,const float* w2,const float* w3,
                             const float* w4,const float* w5,const float* w6,const float* w7,
                             unsigned short* dst){
  int w = blockIdx.y;
  const float* src;
  switch(w){
    case 0: src=w0; break; case 1: src=w1; break; case 2: src=w2; break; case 3: src=w3; break;
    case 4: src=w4; break; case 5: src=w5; break; case 6: src=w6; break; default: src=w7; break;
  }
  int i = blockIdx.x*256 + threadIdx.x;
  float v = src[i];
  if(w==0 || w==4 || w==1 || w==5) v *= 0.32267249f;   // sqrt(log2(e)/sqrt(192))
  dst[(size_t)w*36864 + i] = f2bf(v);
}

// ---------------- fused QKV projection, split by path ----------------
// Q8 fp8 [row][192]; K fp8 tile images [path][b][64][64][200B];
// V fp8 tile images [path][b][64][192][72B]. Q/K use SWAPPED mfma operands
// (W-frag and x-frag registers are valid as either A or B): lane then holds
// 4 consecutive OUTPUT COLUMNS of one row -> pk8 quad -> single 4B store
// (12 x 4B instead of 48 x 1B scattered).
__global__ __launch_bounds__(256) void proj_kernel(
    const float* __restrict__ x, const unsigned short* __restrict__ Wb,
    unsigned char* __restrict__ Q8g, unsigned char* __restrict__ K8t,
    unsigned char* __restrict__ V8)
{
  __shared__ __align__(16) unsigned char Vstage8[VTILE];   // 13.8 KB
  const size_t MDB = (size_t)M_*D_;
  int path = blockIdx.y;
  int tid = threadIdx.x;
  int wid = tid>>6, lane = tid&63;
  int lr = lane&15, lg = lane>>4, kb = lg*8;
  int m0 = blockIdx.x*64 + wid*16;
  int row = m0 + lr;

  v8s a[6];
  #pragma unroll
  for(int c=0;c<6;c++){
    const float* xp = &x[(size_t)row*D_ + c*32 + kb];
    float4 f0 = *(const float4*)xp;
    float4 f1 = *(const float4*)(xp+4);
    v8s t;
    t[0]=(short)f2bf(f0.x); t[1]=(short)f2bf(f0.y); t[2]=(short)f2bf(f0.z); t[3]=(short)f2bf(f0.w);
    t[4]=(short)f2bf(f1.x); t[5]=(short)f2bf(f1.y); t[6]=(short)f2bf(f1.z); t[7]=(short)f2bf(f1.w);
    a[c]=t;
  }
  int bidx = m0 / S_;
  int sb   = (blockIdx.x*64) % S_;       // block s-base = one 64-row tile
  int tile = sb >> 6;
  int sloc = wid*16 + lg*4;              // local s (0..63), for V stage

  // ---- Q: swapped operands -> out[row=m0+lr][cols nt*16+lg*4..+3] ----
  {
    const unsigned short* W = Wb + (size_t)(path*4 + 0)*36864;
    unsigned char* dst = Q8g + (size_t)path*MDB + (size_t)(m0+lr)*D_;
    #pragma unroll
    for(int nt=0; nt<12; nt++){
      v4f acc = {0.f,0.f,0.f,0.f};
      int n = nt*16 + lr;
      #pragma unroll
      for(int c=0;c<6;c++){
        v8s bfr = *(const v8s*)&W[(size_t)n*D_ + c*32 + kb];
        acc = __builtin_amdgcn_mfma_f32_16x16x32_bf16(bfr, a[c], acc, 0,0,0);
      }
      unsigned pk4 = pk8<false>(acc[0], acc[1], 0u);
      pk4 = pk8<true>(acc[2], acc[3], pk4);
      *(unsigned*)&dst[nt*16 + lg*4] = pk4;
    }
  }
  // ---- K: swapped operands -> tile image [s=wid*16+lr][cols] ----
  {
    const unsigned short* W = Wb + (size_t)(path*4 + 1)*36864;
    unsigned char* dstK = K8t + (((size_t)path*B_ + bidx)*NT_ + tile)*KTILE
                        + (size_t)(wid*16 + lr)*200;
    #pragma unroll
    for(int nt=0; nt<12; nt++){
      v4f acc = {0.f,0.f,0.f,0.f};
      int n = nt*16 + lr;
      #pragma unroll
      for(int c=0;c<6;c++){
        v8s bfr = *(const v8s*)&W[(size_t)n*D_ + c*32 + kb];
        acc = __builtin_amdgcn_mfma_f32_16x16x32_bf16(bfr, a[c], acc, 0,0,0);
      }
      unsigned pk4 = pk8<false>(acc[0], acc[1], 0u);
      pk4 = pk8<true>(acc[2], acc[3], pk4);
      *(unsigned*)&dstK[nt*16 + lg*4] = pk4;
    }
  }
  // ---- V: unswapped (4 consecutive s per thread) -> LDS stage -> linear ----
  {
    const unsigned short* W = Wb + (size_t)(path*4 + 2)*36864;
    #pragma unroll
    for(int nt=0; nt<12; nt++){
      v4f acc = {0.f,0.f,0.f,0.f};
      int n = nt*16 + lr;
      #pragma unroll
      for(int c=0;c<6;c++){
        v8s bfr = *(const v8s*)&W[(size_t)n*D_ + c*32 + kb];
        acc = __builtin_amdgcn_mfma_f32_16x16x32_bf16(a[c], bfr, acc, 0,0,0);
      }
      int col = nt*16 + lr;
      unsigned pk4 = pk8<false>(acc[0], acc[1], 0u);
      pk4 = pk8<true>(acc[2], acc[3], pk4);
      *(unsigned*)&Vstage8[col*72 + sloc] = pk4;
    }
    __syncthreads();
    unsigned char* dstV = V8 + (((size_t)path*B_ + bidx)*NT_ + tile)*VTILE;
    #pragma unroll
    for(int j=0;j<4;j++){
      int i = tid + j*256;                 // 864 chunks of 16B
      if(i<864) *(v8s*)&dstV[i*16] = *(const v8s*)&Vstage8[i*16];
    }
  }
}

// ---------------- flash attention: fp8, tile 64 (round-29 proven) -----------
// grid (32,8,2) XCD-remapped, 512 thr (8w x 16q). 64 iterations.
// K LDS [64][200B], V LDS [192][72B]; K dbuf, V tribuf; vmcnt(0)+barrier/tile.
__global__ __launch_bounds__(512,4) void attn_kernel(
    const unsigned char* __restrict__ Q8g,
    const unsigned char* __restrict__ K8t,
    const unsigned char* __restrict__ V8,
    unsigned short* __restrict__ Ob)
{
  __shared__ __align__(16) unsigned char KL[2][KTILE];      // 25.6 KB
  __shared__ __align__(16) unsigned char VL8[3][VTILE];     // 41.5 KB (67 KB)

  int flat = blockIdx.x + 32*blockIdx.y + 256*blockIdx.z;
  int w = (flat&7)*64 + (flat>>3);   // bijective on [0,512)
  int qi = w & 31;
  int b  = (w>>5) & 7;
  int z  = w>>8;

  const size_t MDB = (size_t)M_*D_;
  const unsigned char* Q8 = Q8g + (size_t)z*MDB;
  const unsigned char* Kp = K8t + ((size_t)z*B_ + b)*NT_*KTILE;
  const unsigned char* Vp = V8 + ((size_t)z*B_ + b)*NT_*VTILE;
  unsigned short* O = Ob + (size_t)z*MDB;

  int q0 = qi*128;
  int tid = threadIdx.x, wid=tid>>6, lane=tid&63;
  int lr = lane&15, lg = lane>>4;
  size_t bK = (size_t)b*S_*D_;
  int qrow0 = q0 + wid*16;

  long qf8[6];
  {
    const unsigned char* qp = Q8 + bK + (size_t)(qrow0 + lr)*D_;
    #pragma unroll
    for(int c=0;c<6;c++) qf8[c] = *(const long*)(qp + c*32 + lg*8);
  }
  float lsum = 0.f;
  v4f oacc[12];
  #pragma unroll
  for(int e=0;e<12;e++) oacc[e] = (v4f){0.f,0.f,0.f,0.f};

  bool k2 = tid < 288;    // 800 K chunks = 512 + 288
  bool v2 = tid < 352;    // 864 V chunks = 512 + 352

  auto stage = [&](int t, int kbuf, int vbuf){
    const unsigned char* kg = Kp + (size_t)t*KTILE;
    const unsigned char* vg = Vp + (size_t)t*VTILE;
    GLL16(kg + tid*16, &KL[kbuf][tid*16]);
    if(k2) GLL16(kg + (512+tid)*16, &KL[kbuf][(512+tid)*16]);
    GLL16(vg + tid*16, &VL8[vbuf][tid*16]);
    if(v2) GLL16(vg + (512+tid)*16, &VL8[vbuf][(512+tid)*16]);
  };
  auto do_qk = [&](int kcur, v4f sacc[4]){
    __builtin_amdgcn_s_setprio(1);
    #pragma unroll
    for(int ct=0; ct<4; ct++){
      v4f s = {0.f,0.f,0.f,0.f};
      const unsigned char* rb = &KL[kcur][(ct*16+lr)*200];
      #pragma unroll
      for(int c=0;c<6;c++){
        long kf8 = *(const long*)(rb + c*32 + lg*8);
        s = __builtin_amdgcn_mfma_f32_16x16x32_fp8_fp8(kf8, qf8[c], s, 0,0,0);
      }
      sacc[ct]=s;
    }
    __builtin_amdgcn_s_setprio(0);
  };
  auto do_softmax = [&](v4f sacc[4], long pa8[2]){
    #pragma unroll
    for(int h=0; h<2; h++){
      v4f s0 = sacc[2*h], s1 = sacc[2*h+1];
      float p00=fexp2(s0[0]), p01=fexp2(s0[1]), p02=fexp2(s0[2]), p03=fexp2(s0[3]);
      float p10=fexp2(s1[0]), p11=fexp2(s1[1]), p12=fexp2(s1[2]), p13=fexp2(s1[3]);
      lsum += ((p00+p01)+(p02+p03)) + ((p10+p11)+(p12+p13));
      unsigned A = pk8<false>(p00,p01,0u); A = pk8<true>(p02,p03,A);
      unsigned Bx= pk8<false>(p10,p11,0u); Bx= pk8<true>(p12,p13,Bx);
      asm("v_permlane32_swap_b32 %0, %1" : "+v"(Bx), "+v"(A));
      asm("v_permlane16_swap_b32 %0, %1" : "+v"(Bx), "+v"(A));
      pa8[h] = (long)(((ull)Bx<<32) | (ull)A);
    }
  };
  auto do_pv = [&](int vcur, long pa8[2]){
    __builtin_amdgcn_s_setprio(1);
    #pragma unroll
    for(int e=0;e<12;e++){
      const unsigned char* vr = &VL8[vcur][(e*16+lr)*72 + lg*8];
      long vb0 = *(const long*)(vr);
      long vb1 = *(const long*)(vr + 32);
      oacc[e] = __builtin_amdgcn_mfma_f32_16x16x32_fp8_fp8(pa8[0], vb0, oacc[e], 0,0,0);
      oacc[e] = __builtin_amdgcn_mfma_f32_16x16x32_fp8_fp8(pa8[1], vb1, oacc[e], 0,0,0);
    }
    __builtin_amdgcn_s_setprio(0);
  };

  stage(0, 0, 0);
  asm volatile("s_waitcnt vmcnt(0)" ::: "memory");
  __syncthreads();

  long pa_prev[2];
  {
    v4f sacc[4];
    do_qk(0, sacc);
    stage(1, 1, 1);
    __builtin_amdgcn_sched_barrier(0);
    do_softmax(sacc, pa_prev);
    asm volatile("s_waitcnt vmcnt(0)" ::: "memory");
    __syncthreads();
  }

  for(int t=1; t<NT_; t++){
    v4f sacc[4];
    do_qk(t&1, sacc);
    if(t<NT_-1) stage(t+1, (t+1)&1, (t+1)%3);
    __builtin_amdgcn_sched_barrier(0);
    do_pv((t-1)%3, pa_prev);
    do_softmax(sacc, pa_prev);
    asm volatile("s_waitcnt vmcnt(0)" ::: "memory");
    __syncthreads();
  }
  do_pv((NT_-1)%3, pa_prev);

  // epilogue: per-lane sums (q-row = lr) -> row inverses -> O write (bf16)
  float ps = lsum;
  ps += __shfl_xor(ps, 16);
  ps += __shfl_xor(ps, 32);
  float iv = 1.0f/ps;
  float invr[4];
  #pragma unroll
  for(int r=0;r<4;r++) invr[r] = __shfl(iv, lg*4+r, 16);
  size_t orow0 = ((size_t)b*S_ + qrow0 + lg*4)*D_;
  #pragma unroll
  for(int e=0;e<12;e++){
    #pragma unroll
    for(int r=0;r<4;r++){
      O[orow0 + (size_t)r*D_ + e*16 + lr] = f2bf(oacc[e][r]*invr[r]);
    }
  }
}

// ---------------- final: swapped operands -> float4 stores ------------------
// grid dim3(512,2). Block computes out cols [96h, 96h+96) for its 64 rows.
// mfma(br, ar): lane holds out[row=m0+lr][cols nt*16+lg*4..+3] -> float4.
__global__ __launch_bounds__(256) void final_kernel(
  const float* __restrict__ x,
  const unsigned short* __restrict__ Or,
  const unsigned short* __restrict__ Ow,
  const unsigned short* __restrict__ WoR,
  const unsigned short* __restrict__ WoW,
  float* __restrict__ out)
{
  int halfn = blockIdx.y;
  int tid=threadIdx.x, wid=tid>>6, lane=tid&63;
  int lr=lane&15, lg=lane>>4, kb=lg*8;
  int m0 = blockIdx.x*64 + wid*16;
  int arow = m0 + lr;
  v8s ar[6], aw[6];
  #pragma unroll
  for(int c=0;c<6;c++){
    ar[c] = *(const v8s*)&Or[(size_t)arow*D_ + c*32 + kb];
    aw[c] = *(const v8s*)&Ow[(size_t)arow*D_ + c*32 + kb];
  }
  int bidx = m0 / S_;
  float rf = x[(size_t)bidx*S_*D_ + 156];
  float wf = x[(size_t)bidx*S_*D_ + 157];
  #pragma unroll
  for(int ntl=0; ntl<6; ntl++){
    int nt = halfn*6 + ntl;
    v4f accR={0.f,0.f,0.f,0.f}, accW={0.f,0.f,0.f,0.f};
    int n = nt*16 + lr;
    #pragma unroll
    for(int c=0;c<6;c++){
      v8s br = *(const v8s*)&WoR[(size_t)n*D_ + c*32 + kb];
      accR = __builtin_amdgcn_mfma_f32_16x16x32_bf16(br, ar[c], accR,0,0,0);
      v8s bw = *(const v8s*)&WoW[(size_t)n*D_ + c*32 + kb];
      accW = __builtin_amdgcn_mfma_f32_16x16x32_bf16(bw, aw[c], accW,0,0,0);
    }
    int col0 = nt*16 + lg*4;
    const float* xp = &x[(size_t)arow*D_ + col0];
    float4 xv = *(const float4*)xp;
    float o[4];
    #pragma unroll
    for(int r=0;r<4;r++){
      float xvj = (&xv.x)[r];
      float val = xvj + rf*(accR[r]-xvj) + wf*(accW[r]-xvj);
      int cj = col0 + r;
      if(cj==156||cj==157) val = 0.f;
      else if(cj==158) val = rf+wf;
      o[r] = val;
    }
    *(float4*)&out[(size_t)arow*D_ + col0] = *(float4*)o;
  }
}

extern "C" void kernel_launch(void* const* d_in, const int* in_sizes, int n_in,
                              void* d_out, int out_size, void* d_ws, size_t ws_size,
                              hipStream_t stream) {
  const float* x = (const float*)d_in[0];
  char* wsb = (char*)d_ws;
  const size_t WSZ = 36864;
  const size_t MDB = (size_t)M_*D_;
  const size_t K8SZ = (size_t)2*B_*NT_*KTILE;                  // 13.1 MB
  const size_t V8SZ = (size_t)2*B_*NT_*VTILE;                  // 14.2 MB
  unsigned short* Wb  = (unsigned short*)wsb;                  // 0.59 MB
  unsigned char*  Q8  = (unsigned char*)(wsb + 8*WSZ*2);       // 12.6 MB
  unsigned char*  K8t = Q8 + 2*MDB;                            // 13.1 MB
  unsigned char*  V8  = K8t + K8SZ;                            // 14.2 MB
  unsigned short* Ob  = (unsigned short*)(V8 + V8SZ);          // 25.2 MB

  cvt_w_kernel<<<dim3(144,8),256,0,stream>>>(
      (const float*)d_in[1],(const float*)d_in[2],(const float*)d_in[3],(const float*)d_in[4],
      (const float*)d_in[5],(const float*)d_in[6],(const float*)d_in[7],(const float*)d_in[8], Wb);

  proj_kernel<<<dim3(512,2),256,0,stream>>>(x, Wb, Q8, K8t, V8);
  attn_kernel<<<dim3(32,8,2),512,0,stream>>>(Q8, K8t, V8, Ob);
  final_kernel<<<dim3(512,2),256,0,stream>>>(x, Ob, Ob + MDB,
                                             Wb+3*WSZ, Wb+7*WSZ, (float*)d_out);
}